// Round 1
// baseline (5191.249 us; speedup 1.0000x reference)
//
#include <hip/hip_runtime.h>

#define NEG_INF (-1e30f)

// ---------------- workspace layout (float offsets) ----------------
#define OFF_X      0         // 10*8192
#define OFF_H1     81920     // 10*4096
#define OFF_H2     122880    // 10*4096
#define OFF_LASTH  163840    // 4096
#define OFF_LOGITS 167936    // 10*32000
#define OFF_TOPKP  487936    // 100
#define OFF_SCORES 488036    // 10
#define OFF_SFLAT  488046    // 510
#define OFF_INTS   488560    // int region: tok100, tflat510, pflat51, cur10, outid10

// ---------------- batched skinny GEMM: C(B,N) += X(B,K) @ W(N,K)^T ----------------
// Block: 256 threads, 64 output rows (j), one k-segment of length L.
// X segment staged in LDS; each 8-lane group handles rows j and j+32.
// C must be pre-initialized (bias or 0); partial sums via atomicAdd.
template<int B>
__global__ __launch_bounds__(256) void gemm_xwT(
    const float* __restrict__ X, const float* __restrict__ W,
    float* __restrict__ C, int N, int K, int L)
{
    extern __shared__ float Xs[];                     // B * L floats
    const int tid = threadIdx.x;
    const int jb  = blockIdx.x;
    const int kbase = blockIdx.y * L;
    const int L4 = L >> 2;
    for (int t = tid; t < B * L4; t += 256) {
        int b = t / L4;
        int o = (t - b * L4) << 2;
        *(float4*)&Xs[b * L + o] = *(const float4*)&X[(size_t)b * K + kbase + o];
    }
    __syncthreads();
    const int jg = tid >> 3, l8 = tid & 7;
    const int j0 = jb * 64 + jg;
    const int j1 = j0 + 32;
    const float* w0p = W + (size_t)j0 * K + kbase;
    const float* w1p = W + (size_t)j1 * K + kbase;
    double a0[B], a1[B];
#pragma unroll
    for (int b = 0; b < B; b++) { a0[b] = 0.0; a1[b] = 0.0; }
    for (int kk = l8 * 4; kk < L; kk += 32) {
        float4 w0 = *(const float4*)(w0p + kk);
        float4 w1 = *(const float4*)(w1p + kk);
#pragma unroll
        for (int b = 0; b < B; b++) {
            float4 x = *(const float4*)&Xs[b * L + kk];
            a0[b] += (double)(w0.x * x.x + w0.y * x.y + w0.z * x.z + w0.w * x.w);
            a1[b] += (double)(w1.x * x.x + w1.y * x.y + w1.z * x.z + w1.w * x.w);
        }
    }
#pragma unroll
    for (int b = 0; b < B; b++) {
        double v0 = a0[b], v1 = a1[b];
        for (int d = 4; d > 0; d >>= 1) {
            v0 += __shfl_down(v0, d, 8);
            v1 += __shfl_down(v1, d, 8);
        }
        if (l8 == 0) {
            atomicAdd(&C[(size_t)b * N + j0], (float)v0);
            atomicAdd(&C[(size_t)b * N + j1], (float)v1);
        }
    }
}

// init three C buffers: H1 <- bfc (broadcast per 4096), H2 <- bm, logits <- 0
__global__ void init3(float* __restrict__ H1, const float* __restrict__ bfc, int n1,
                      float* __restrict__ H2, const float* __restrict__ bm, int n2,
                      float* __restrict__ Lg, int n3)
{
    int i = blockIdx.x * 256 + threadIdx.x;
    if (i < n1) H1[i] = bfc[i & 4095];
    else if (i < n1 + n2) H2[i - n1] = bm[(i - n1) & 4095];
    else if (i < n1 + n2 + n3) Lg[i - n1 - n2] = 0.f;
}

__global__ void tanh_k(float* __restrict__ A, int n)
{
    int i = blockIdx.x * 256 + threadIdx.x;
    if (i < n) A[i] = tanhf(A[i]);
}

// X[b] = concat(W_embed[tok[b]], Hsrc[rows ? rows[b] : 0])
__global__ void build_x(float* __restrict__ X, const float* __restrict__ Wemb,
                        const int* __restrict__ tok, const float* __restrict__ Hsrc,
                        const int* __restrict__ rows, int B)
{
    int q = blockIdx.x * 256 + threadIdx.x;   // float4 index
    const int per = 2048;                      // 8192/4
    if (q >= B * per) return;
    int b = q / per;
    int col = (q - b * per) * 4;
    float4 v;
    if (col < 4096) v = *(const float4*)&Wemb[(size_t)tok[b] * 4096 + col];
    else {
        int r = rows ? rows[b] : 0;
        v = *(const float4*)&Hsrc[(size_t)r * 4096 + (col - 4096)];
    }
    *(float4*)&X[(size_t)b * 8192 + col] = v;
}

// per-row: lse over 32000 logits, then stable top-10 (ties -> lowest index)
__global__ __launch_bounds__(256) void topk_rows(const float* __restrict__ logits,
        float* __restrict__ topk_p, int* __restrict__ topk_tok)
{
    const int row = blockIdx.x, tid = threadIdx.x;
    const float* Lr = logits + (size_t)row * 32000;
    __shared__ float sred[4];
    __shared__ int sredi[4];
    __shared__ float sbc;
    __shared__ int chosen[10];
    // max
    float m = NEG_INF;
    for (int v = tid; v < 32000; v += 256) m = fmaxf(m, Lr[v]);
    for (int d = 32; d; d >>= 1) m = fmaxf(m, __shfl_down(m, d, 64));
    if ((tid & 63) == 0) sred[tid >> 6] = m;
    __syncthreads();
    if (tid == 0) { float mm = sred[0]; for (int w = 1; w < 4; w++) mm = fmaxf(mm, sred[w]); sbc = mm; }
    __syncthreads();
    float maxv = sbc;
    // sum exp
    float s = 0.f;
    for (int v = tid; v < 32000; v += 256) s += expf(Lr[v] - maxv);
    for (int d = 32; d; d >>= 1) s += __shfl_down(s, d, 64);
    if ((tid & 63) == 0) sred[tid >> 6] = s;
    __syncthreads();
    if (tid == 0) sbc = maxv + logf(sred[0] + sred[1] + sred[2] + sred[3]);
    __syncthreads();
    float lse = sbc;
    // 10 stable argmax passes
    for (int t = 0; t < 10; t++) {
        float bv = NEG_INF; int bi = 0x7fffffff;
        for (int v = tid; v < 32000; v += 256) {
            float val = Lr[v];
            bool skip = false;
            for (int u = 0; u < t; u++) skip |= (chosen[u] == v);
            if (!skip && (val > bv || (val == bv && v < bi))) { bv = val; bi = v; }
        }
        for (int d = 32; d; d >>= 1) {
            float ov = __shfl_down(bv, d, 64); int oi = __shfl_down(bi, d, 64);
            if (ov > bv || (ov == bv && oi < bi)) { bv = ov; bi = oi; }
        }
        if ((tid & 63) == 0) { sred[tid >> 6] = bv; sredi[tid >> 6] = bi; }
        __syncthreads();
        if (tid == 0) {
            float fv = sred[0]; int fi = sredi[0];
            for (int w = 1; w < 4; w++)
                if (sred[w] > fv || (sred[w] == fv && sredi[w] < fi)) { fv = sred[w]; fi = sredi[w]; }
            chosen[t] = fi;
            topk_p[row * 10 + t] = fv - lse;
            topk_tok[row * 10 + t] = fi;
        }
        __syncthreads();
    }
}

__global__ void orch_init(const float* __restrict__ topk_p, const int* __restrict__ topk_tok,
                          float* __restrict__ scores, float* __restrict__ sflat,
                          int* __restrict__ tflat, int* __restrict__ pflat,
                          int* __restrict__ cur, int* __restrict__ outid)
{
    int t = threadIdx.x;
    if (t < 10) {
        float v = topk_p[t]; int k = topk_tok[t];
        scores[t] = v; sflat[t] = v; tflat[t] = k; cur[t] = k; outid[t] = 0;
    }
    if (t == 0) pflat[0] = 0;
}

__global__ __launch_bounds__(128) void orch_iter(const float* __restrict__ topk_p,
        const int* __restrict__ topk_tok, float* __restrict__ scores,
        float* __restrict__ sflat, int* __restrict__ tflat, int* __restrict__ pflat,
        int* __restrict__ cur, int* __restrict__ outid, int iter)
{
    __shared__ float cu[100];
    __shared__ float csp[10];
    __shared__ int csi[10];
    __shared__ float pv[2];
    __shared__ int pi[2];
    int tid = threadIdx.x;
    if (tid < 100) {
        float v = topk_p[tid] + scores[tid / 10];
        cu[tid] = v;
        sflat[10 + iter * 100 + tid] = v;
        tflat[10 + iter * 100 + tid] = topk_tok[tid];
    }
    __syncthreads();
    for (int t = 0; t < 10; t++) {
        float bv = (tid < 100) ? cu[tid] : NEG_INF;
        int bi = tid;
        for (int d = 32; d; d >>= 1) {
            float ov = __shfl_down(bv, d, 64); int oi = __shfl_down(bi, d, 64);
            if (ov > bv || (ov == bv && oi < bi)) { bv = ov; bi = oi; }
        }
        if ((tid & 63) == 0) { pv[tid >> 6] = bv; pi[tid >> 6] = bi; }
        __syncthreads();
        if (tid == 0) {
            float fv = pv[0]; int fi = pi[0];
            if (pv[1] > fv || (pv[1] == fv && pi[1] < fi)) { fv = pv[1]; fi = pi[1]; }
            csp[t] = fv; csi[t] = fi; cu[fi] = NEG_INF;
        }
        __syncthreads();
    }
    if (tid < 10) {
        int ci = csi[tid];
        scores[tid] = csp[tid];
        int bias2 = (iter - 1 > 0) ? (iter - 1) : 0;
        int bias = 1 + 100 * bias2 + ((iter > 0) ? 10 : 0);
        pflat[1 + iter * 10 + tid] = ci + bias;
        outid[tid] = ci / 10;
        cur[tid] = topk_tok[ci];
    }
}

// top-59 of 510 (stable), sort indices, gather outputs, build tree mask
__global__ __launch_bounds__(64) void finalize(const float* __restrict__ sflat,
        const int* __restrict__ tflat, const int* __restrict__ pflat,
        const int* __restrict__ input_ids, float* __restrict__ out)
{
    __shared__ float vals[510];
    __shared__ int flag[510];
    __shared__ int tidx[59];
    __shared__ int mski[59];
    __shared__ int tm[60 * 60];
    int tid = threadIdx.x;  // 64
    for (int i = tid; i < 510; i += 64) { vals[i] = sflat[i]; flag[i] = 0; }
    __syncthreads();
    for (int t = 0; t < 59; t++) {
        float bv = NEG_INF; int bi = 1 << 30;
        for (int i = tid; i < 510; i += 64) {
            float v = vals[i];
            if (v > bv || (v == bv && i < bi)) { bv = v; bi = i; }
        }
        for (int d = 32; d; d >>= 1) {
            float ov = __shfl_down(bv, d, 64); int oi = __shfl_down(bi, d, 64);
            if (ov > bv || (ov == bv && oi < bi)) { bv = ov; bi = oi; }
        }
        if (tid == 0) { vals[bi] = NEG_INF; flag[bi] = 1; }
        __syncthreads();
    }
    if (tid == 0) {
        int n = 0;
        for (int i = 0; i < 510; i++) if (flag[i]) tidx[n++] = i;
    }
    __syncthreads();
    if (tid < 59) {
        int ti = tidx[tid];
        out[60 + tid] = sflat[ti];                 // top_vals
        out[1 + tid] = (float)tflat[ti];           // draft_tokens[1:]
        int par = pflat[ti / 10];
        int mi;
        if (par == 0) mi = 0;
        else {
            int v = par - 1, lo = 0, hi = 59;      // searchsorted left
            while (lo < hi) { int mid = (lo + hi) >> 1; if (tidx[mid] < v) lo = mid + 1; else hi = mid; }
            mi = lo + 1;
        }
        mski[tid] = mi;
    }
    if (tid == 0) out[0] = (float)input_ids[1024]; // sample_token
    __syncthreads();
    for (int i = tid; i < 3600; i += 64) {
        int r = i / 60, c = i - r * 60;
        tm[i] = (r == c || c == 0) ? 1 : 0;
    }
    __syncthreads();
    for (int i = 0; i < 59; i++) {
        int src = mski[i]; if (src > 59) src = 59;  // jax OOB clamp
        if (tid < 60) tm[(i + 1) * 60 + tid] |= tm[src * 60 + tid];
        __syncthreads();
    }
    if (tid < 60) {
        int s = 0;
        for (int c = 0; c < 60; c++) s += tm[tid * 60 + c];
        out[3719 + tid] = (float)(s - 1);           // tree_position_ids
    }
    for (int i = tid; i < 3600; i += 64) out[119 + i] = (float)tm[i];  // tree_mask
}

extern "C" void kernel_launch(void* const* d_in, const int* in_sizes, int n_in,
                              void* d_out, int out_size, void* d_ws, size_t ws_size,
                              hipStream_t stream)
{
    const float* hidden    = (const float*)d_in[0];
    const int*   input_ids = (const int*)d_in[1];
    const float* Wemb      = (const float*)d_in[2];
    const float* Whead     = (const float*)d_in[3];
    const float* Wfc       = (const float*)d_in[4];
    const float* bfc       = (const float*)d_in[5];
    const float* Wm        = (const float*)d_in[6];
    const float* bm        = (const float*)d_in[7];
    float* out = (float*)d_out;
    float* ws  = (float*)d_ws;

    float* X      = ws + OFF_X;
    float* H1     = ws + OFF_H1;
    float* H2     = ws + OFF_H2;
    float* lastH  = ws + OFF_LASTH;
    float* logits = ws + OFF_LOGITS;
    float* topkp  = ws + OFF_TOPKP;
    float* scores = ws + OFF_SCORES;
    float* sflat  = ws + OFF_SFLAT;
    int* ibase = (int*)(ws + OFF_INTS);
    int* toktk = ibase;        // 100
    int* tflat = ibase + 100;  // 510
    int* pflat = ibase + 610;  // 51
    int* cur   = ibase + 661;  // 10
    int* outid = ibase + 671;  // 10

    // ---- Phase 0: draft step for LAST position only (rest of reference's S-GEMM is dead) ----
    build_x<<<8, 256, 0, stream>>>(X, Wemb, input_ids + 1024, hidden + 1023 * 4096, nullptr, 1);
    init3<<<(4096 + 4096 + 32000 + 255) / 256, 256, 0, stream>>>(H1, bfc, 4096, lastH, bm, 4096, logits, 32000);
    gemm_xwT<1><<<dim3(64, 8), 256, 1024 * 4, stream>>>(X, Wfc, H1, 4096, 8192, 1024);
    gemm_xwT<1><<<dim3(64, 4), 256, 1024 * 4, stream>>>(H1, Wm, lastH, 4096, 4096, 1024);
    tanh_k<<<16, 256, 0, stream>>>(lastH, 4096);
    // ---- Phase 1: head + first top-k ----
    gemm_xwT<1><<<dim3(500, 4), 256, 1024 * 4, stream>>>(lastH, Whead, logits, 32000, 4096, 1024);
    topk_rows<<<1, 256, 0, stream>>>(logits, topkp, toktk);
    orch_init<<<1, 64, 0, stream>>>(topkp, toktk, scores, sflat, tflat, pflat, cur, outid);
    build_x<<<80, 256, 0, stream>>>(X, Wemb, cur, lastH, nullptr, 10);

    // ---- Tree expansion loop ----
    for (int i = 0; i < 5; i++) {
        init3<<<(40960 + 40960 + 320000 + 255) / 256, 256, 0, stream>>>(H1, bfc, 40960, H2, bm, 40960, logits, 320000);
        gemm_xwT<10><<<dim3(64, 8), 256, 10 * 1024 * 4, stream>>>(X, Wfc, H1, 4096, 8192, 1024);
        gemm_xwT<10><<<dim3(64, 4), 256, 10 * 1024 * 4, stream>>>(H1, Wm, H2, 4096, 4096, 1024);
        tanh_k<<<160, 256, 0, stream>>>(H2, 40960);
        gemm_xwT<10><<<dim3(500, 4), 256, 10 * 1024 * 4, stream>>>(H2, Whead, logits, 32000, 4096, 1024);
        topk_rows<<<10, 256, 0, stream>>>(logits, topkp, toktk);
        orch_iter<<<1, 128, 0, stream>>>(topkp, toktk, scores, sflat, tflat, pflat, cur, outid, i);
        if (i < 4) build_x<<<80, 256, 0, stream>>>(X, Wemb, cur, H2, outid, 10);
    }
    finalize<<<1, 64, 0, stream>>>(sflat, tflat, pflat, input_ids, out);
}

// Round 2
// 3293.040 us; speedup vs baseline: 1.5764x; 1.5764x over previous
//
#include <hip/hip_runtime.h>

#define NEG_INF (-1e30f)

// ---------------- workspace layout (float offsets) ----------------
#define OFF_X      0         // 10*8192
#define OFF_H1     81920     // 10*4096
#define OFF_H2     122880    // 10*4096
#define OFF_LASTH  163840    // 4096
#define OFF_LOGITS 167936    // 10*32000
#define OFF_TOPKP  487936    // 100
#define OFF_SCORES 488036    // 10
#define OFF_SFLAT  488046    // 510
#define OFF_INTS   488560    // int region: tok100, tflat510, pflat51, cur10, outid10

// ---------------- batched skinny GEMM: C(B,N) += X(B,K) @ W(N,K)^T ----------------
template<int B>
__global__ __launch_bounds__(256) void gemm_xwT(
    const float* __restrict__ X, const float* __restrict__ W,
    float* __restrict__ C, int N, int K, int L)
{
    extern __shared__ float Xs[];                     // B * L floats
    const int tid = threadIdx.x;
    const int jb  = blockIdx.x;
    const int kbase = blockIdx.y * L;
    const int L4 = L >> 2;
    for (int t = tid; t < B * L4; t += 256) {
        int b = t / L4;
        int o = (t - b * L4) << 2;
        *(float4*)&Xs[b * L + o] = *(const float4*)&X[(size_t)b * K + kbase + o];
    }
    __syncthreads();
    const int jg = tid >> 3, l8 = tid & 7;
    const int j0 = jb * 64 + jg;
    const int j1 = j0 + 32;
    const float* w0p = W + (size_t)j0 * K + kbase;
    const float* w1p = W + (size_t)j1 * K + kbase;
    double a0[B], a1[B];
#pragma unroll
    for (int b = 0; b < B; b++) { a0[b] = 0.0; a1[b] = 0.0; }
    for (int kk = l8 * 4; kk < L; kk += 32) {
        float4 w0 = *(const float4*)(w0p + kk);
        float4 w1 = *(const float4*)(w1p + kk);
#pragma unroll
        for (int b = 0; b < B; b++) {
            float4 x = *(const float4*)&Xs[b * L + kk];
            a0[b] += (double)(w0.x * x.x + w0.y * x.y + w0.z * x.z + w0.w * x.w);
            a1[b] += (double)(w1.x * x.x + w1.y * x.y + w1.z * x.z + w1.w * x.w);
        }
    }
#pragma unroll
    for (int b = 0; b < B; b++) {
        double v0 = a0[b], v1 = a1[b];
        for (int d = 4; d > 0; d >>= 1) {
            v0 += __shfl_down(v0, d, 8);
            v1 += __shfl_down(v1, d, 8);
        }
        if (l8 == 0) {
            atomicAdd(&C[(size_t)b * N + j0], (float)v0);
            atomicAdd(&C[(size_t)b * N + j1], (float)v1);
        }
    }
}

// init three C buffers: H1 <- bfc (broadcast per 4096), H2 <- bm, logits <- 0
__global__ void init3(float* __restrict__ H1, const float* __restrict__ bfc, int n1,
                      float* __restrict__ H2, const float* __restrict__ bm, int n2,
                      float* __restrict__ Lg, int n3)
{
    int i = blockIdx.x * 256 + threadIdx.x;
    if (i < n1) H1[i] = bfc[i & 4095];
    else if (i < n1 + n2) H2[i - n1] = bm[(i - n1) & 4095];
    else if (i < n1 + n2 + n3) Lg[i - n1 - n2] = 0.f;
}

__global__ void tanh_k(float* __restrict__ A, int n)
{
    int i = blockIdx.x * 256 + threadIdx.x;
    if (i < n) A[i] = tanhf(A[i]);
}

// X[b] = concat(W_embed[tok[b]], Hsrc[rows ? rows[b] : 0])
__global__ void build_x(float* __restrict__ X, const float* __restrict__ Wemb,
                        const int* __restrict__ tok, const float* __restrict__ Hsrc,
                        const int* __restrict__ rows, int B)
{
    int q = blockIdx.x * 256 + threadIdx.x;   // float4 index
    const int per = 2048;                      // 8192/4
    if (q >= B * per) return;
    int b = q / per;
    int col = (q - b * per) * 4;
    float4 v;
    if (col < 4096) v = *(const float4*)&Wemb[(size_t)tok[b] * 4096 + col];
    else {
        int r = rows ? rows[b] : 0;
        v = *(const float4*)&Hsrc[(size_t)r * 4096 + (col - 4096)];
    }
    *(float4*)&X[(size_t)b * 8192 + col] = v;
}

// single-scan stable top-10 + lse per row.
// Pass 1: per-thread register top-10 (value desc, index asc) over float4 loads,
//         then 2560-candidate LDS merge (10 stable selection rounds).
// Pass 2: sum exp(x - max) (L2-hot rescan), double accumulation.
#define TRY_INSERT(vv, ii) do {                                               \
    float _v = (vv); int _i = (ii);                                           \
    if (_v > tv[9] || (_v == tv[9] && _i < ti[9])) {                          \
        _Pragma("unroll")                                                     \
        for (int p = 9; p > 0; p--) {                                         \
            bool up   = (_v > tv[p-1]) || (_v == tv[p-1] && _i < ti[p-1]);    \
            bool here = (_v > tv[p])   || (_v == tv[p]   && _i < ti[p]);      \
            tv[p] = up ? tv[p-1] : (here ? _v : tv[p]);                       \
            ti[p] = up ? ti[p-1] : (here ? _i : ti[p]);                       \
        }                                                                     \
        if ((_v > tv[0]) || (_v == tv[0] && _i < ti[0])) { tv[0] = _v; ti[0] = _i; } \
    }                                                                         \
} while (0)

__global__ __launch_bounds__(256) void topk_rows(const float* __restrict__ logits,
        float* __restrict__ topk_p, int* __restrict__ topk_tok)
{
    const int row = blockIdx.x, tid = threadIdx.x;
    const float* Lr = logits + (size_t)row * 32000;
    __shared__ float sv[2560];
    __shared__ int   si[2560];
    __shared__ float cv[10];
    __shared__ int   ci[10];
    __shared__ float pv[4];
    __shared__ int   pi[4];
    __shared__ double dred[4];
    __shared__ float sbc;

    float tv[10]; int ti[10];
#pragma unroll
    for (int p = 0; p < 10; p++) { tv[p] = NEG_INF; ti[p] = 0x7fffffff; }

    // pass 1: scan 8000 float4s, maintain register top-10
    for (int q = tid; q < 8000; q += 256) {
        float4 x = ((const float4*)Lr)[q];
        int base = q << 2;
        TRY_INSERT(x.x, base);
        TRY_INSERT(x.y, base + 1);
        TRY_INSERT(x.z, base + 2);
        TRY_INSERT(x.w, base + 3);
    }
#pragma unroll
    for (int p = 0; p < 10; p++) { sv[tid * 10 + p] = tv[p]; si[tid * 10 + p] = ti[p]; }
    __syncthreads();

    // 10 stable selection rounds over the 2560 candidates
    for (int t = 0; t < 10; t++) {
        float bv = NEG_INF; int bi = 0x7fffffff;
        for (int r = 0; r < 10; r++) {
            int s = tid + r * 256;
            float v = sv[s]; int idx = si[s];
            if (v > bv || (v == bv && idx < bi)) { bv = v; bi = idx; }
        }
        for (int d = 32; d; d >>= 1) {
            float ov = __shfl_down(bv, d, 64); int oi = __shfl_down(bi, d, 64);
            if (ov > bv || (ov == bv && oi < bi)) { bv = ov; bi = oi; }
        }
        if ((tid & 63) == 0) { pv[tid >> 6] = bv; pi[tid >> 6] = bi; }
        __syncthreads();
        if (tid == 0) {
            float fv = pv[0]; int fi = pi[0];
            for (int w = 1; w < 4; w++)
                if (pv[w] > fv || (pv[w] == fv && pi[w] < fi)) { fv = pv[w]; fi = pi[w]; }
            cv[t] = fv; ci[t] = fi;
        }
        __syncthreads();
        // mark the winner slot (vocab indices are unique across candidates)
        int win = ci[t];
        for (int r = 0; r < 10; r++) {
            int s = tid + r * 256;
            if (si[s] == win) sv[s] = NEG_INF;
        }
        __syncthreads();
    }

    // pass 2: lse = max + log(sum exp(x - max)), double accumulation
    float maxv = cv[0];
    double s = 0.0;
    for (int q = tid; q < 8000; q += 256) {
        float4 x = ((const float4*)Lr)[q];
        s += (double)expf(x.x - maxv) + (double)expf(x.y - maxv)
           + (double)expf(x.z - maxv) + (double)expf(x.w - maxv);
    }
    for (int d = 32; d; d >>= 1) s += __shfl_down(s, d, 64);
    if ((tid & 63) == 0) dred[tid >> 6] = s;
    __syncthreads();
    if (tid == 0) sbc = maxv + (float)log(dred[0] + dred[1] + dred[2] + dred[3]);
    __syncthreads();
    if (tid < 10) {
        topk_p[row * 10 + tid] = cv[tid] - sbc;
        topk_tok[row * 10 + tid] = ci[tid];
    }
}

__global__ void orch_init(const float* __restrict__ topk_p, const int* __restrict__ topk_tok,
                          float* __restrict__ scores, float* __restrict__ sflat,
                          int* __restrict__ tflat, int* __restrict__ pflat,
                          int* __restrict__ cur, int* __restrict__ outid)
{
    int t = threadIdx.x;
    if (t < 10) {
        float v = topk_p[t]; int k = topk_tok[t];
        scores[t] = v; sflat[t] = v; tflat[t] = k; cur[t] = k; outid[t] = 0;
    }
    if (t == 0) pflat[0] = 0;
}

__global__ __launch_bounds__(128) void orch_iter(const float* __restrict__ topk_p,
        const int* __restrict__ topk_tok, float* __restrict__ scores,
        float* __restrict__ sflat, int* __restrict__ tflat, int* __restrict__ pflat,
        int* __restrict__ cur, int* __restrict__ outid, int iter)
{
    __shared__ float cu[100];
    __shared__ float csp[10];
    __shared__ int csi[10];
    __shared__ float pv[2];
    __shared__ int pi[2];
    int tid = threadIdx.x;
    if (tid < 100) {
        float v = topk_p[tid] + scores[tid / 10];
        cu[tid] = v;
        sflat[10 + iter * 100 + tid] = v;
        tflat[10 + iter * 100 + tid] = topk_tok[tid];
    }
    __syncthreads();
    for (int t = 0; t < 10; t++) {
        float bv = (tid < 100) ? cu[tid] : NEG_INF;
        int bi = tid;
        for (int d = 32; d; d >>= 1) {
            float ov = __shfl_down(bv, d, 64); int oi = __shfl_down(bi, d, 64);
            if (ov > bv || (ov == bv && oi < bi)) { bv = ov; bi = oi; }
        }
        if ((tid & 63) == 0) { pv[tid >> 6] = bv; pi[tid >> 6] = bi; }
        __syncthreads();
        if (tid == 0) {
            float fv = pv[0]; int fi = pi[0];
            if (pv[1] > fv || (pv[1] == fv && pi[1] < fi)) { fv = pv[1]; fi = pi[1]; }
            csp[t] = fv; csi[t] = fi; cu[fi] = NEG_INF;
        }
        __syncthreads();
    }
    if (tid < 10) {
        int ci = csi[tid];
        scores[tid] = csp[tid];
        int bias2 = (iter - 1 > 0) ? (iter - 1) : 0;
        int bias = 1 + 100 * bias2 + ((iter > 0) ? 10 : 0);
        pflat[1 + iter * 10 + tid] = ci + bias;
        outid[tid] = ci / 10;
        cur[tid] = topk_tok[ci];
    }
}

// top-59 of 510 (stable), sort indices, gather outputs, build tree mask
__global__ __launch_bounds__(64) void finalize(const float* __restrict__ sflat,
        const int* __restrict__ tflat, const int* __restrict__ pflat,
        const int* __restrict__ input_ids, float* __restrict__ out)
{
    __shared__ float vals[510];
    __shared__ int flag[510];
    __shared__ int tidx[59];
    __shared__ int mski[59];
    __shared__ int tm[60 * 60];
    int tid = threadIdx.x;  // 64
    for (int i = tid; i < 510; i += 64) { vals[i] = sflat[i]; flag[i] = 0; }
    __syncthreads();
    for (int t = 0; t < 59; t++) {
        float bv = NEG_INF; int bi = 1 << 30;
        for (int i = tid; i < 510; i += 64) {
            float v = vals[i];
            if (v > bv || (v == bv && i < bi)) { bv = v; bi = i; }
        }
        for (int d = 32; d; d >>= 1) {
            float ov = __shfl_down(bv, d, 64); int oi = __shfl_down(bi, d, 64);
            if (ov > bv || (ov == bv && oi < bi)) { bv = ov; bi = oi; }
        }
        if (tid == 0) { vals[bi] = NEG_INF; flag[bi] = 1; }
        __syncthreads();
    }
    if (tid == 0) {
        int n = 0;
        for (int i = 0; i < 510; i++) if (flag[i]) tidx[n++] = i;
    }
    __syncthreads();
    if (tid < 59) {
        int ti = tidx[tid];
        out[60 + tid] = sflat[ti];                 // top_vals
        out[1 + tid] = (float)tflat[ti];           // draft_tokens[1:]
        int par = pflat[ti / 10];
        int mi;
        if (par == 0) mi = 0;
        else {
            int v = par - 1, lo = 0, hi = 59;      // searchsorted left
            while (lo < hi) { int mid = (lo + hi) >> 1; if (tidx[mid] < v) lo = mid + 1; else hi = mid; }
            mi = lo + 1;
        }
        mski[tid] = mi;
    }
    if (tid == 0) out[0] = (float)input_ids[1024]; // sample_token
    __syncthreads();
    for (int i = tid; i < 3600; i += 64) {
        int r = i / 60, c = i - r * 60;
        tm[i] = (r == c || c == 0) ? 1 : 0;
    }
    __syncthreads();
    for (int i = 0; i < 59; i++) {
        int src = mski[i]; if (src > 59) src = 59;  // jax OOB clamp
        if (tid < 60) tm[(i + 1) * 60 + tid] |= tm[src * 60 + tid];
        __syncthreads();
    }
    if (tid < 60) {
        int s = 0;
        for (int c = 0; c < 60; c++) s += tm[tid * 60 + c];
        out[3719 + tid] = (float)(s - 1);           // tree_position_ids
    }
    for (int i = tid; i < 3600; i += 64) out[119 + i] = (float)tm[i];  // tree_mask
}

extern "C" void kernel_launch(void* const* d_in, const int* in_sizes, int n_in,
                              void* d_out, int out_size, void* d_ws, size_t ws_size,
                              hipStream_t stream)
{
    const float* hidden    = (const float*)d_in[0];
    const int*   input_ids = (const int*)d_in[1];
    const float* Wemb      = (const float*)d_in[2];
    const float* Whead     = (const float*)d_in[3];
    const float* Wfc       = (const float*)d_in[4];
    const float* bfc       = (const float*)d_in[5];
    const float* Wm        = (const float*)d_in[6];
    const float* bm        = (const float*)d_in[7];
    float* out = (float*)d_out;
    float* ws  = (float*)d_ws;

    float* X      = ws + OFF_X;
    float* H1     = ws + OFF_H1;
    float* H2     = ws + OFF_H2;
    float* lastH  = ws + OFF_LASTH;
    float* logits = ws + OFF_LOGITS;
    float* topkp  = ws + OFF_TOPKP;
    float* scores = ws + OFF_SCORES;
    float* sflat  = ws + OFF_SFLAT;
    int* ibase = (int*)(ws + OFF_INTS);
    int* toktk = ibase;        // 100
    int* tflat = ibase + 100;  // 510
    int* pflat = ibase + 610;  // 51
    int* cur   = ibase + 661;  // 10
    int* outid = ibase + 671;  // 10

    // ---- Phase 0: draft step for LAST position only (rest of reference's S-GEMM is dead) ----
    build_x<<<8, 256, 0, stream>>>(X, Wemb, input_ids + 1024, hidden + 1023 * 4096, nullptr, 1);
    init3<<<(4096 + 4096 + 32000 + 255) / 256, 256, 0, stream>>>(H1, bfc, 4096, lastH, bm, 4096, logits, 32000);
    gemm_xwT<1><<<dim3(64, 8), 256, 1024 * 4, stream>>>(X, Wfc, H1, 4096, 8192, 1024);
    gemm_xwT<1><<<dim3(64, 4), 256, 1024 * 4, stream>>>(H1, Wm, lastH, 4096, 4096, 1024);
    tanh_k<<<16, 256, 0, stream>>>(lastH, 4096);
    // ---- Phase 1: head + first top-k ----
    gemm_xwT<1><<<dim3(500, 4), 256, 1024 * 4, stream>>>(lastH, Whead, logits, 32000, 4096, 1024);
    topk_rows<<<1, 256, 0, stream>>>(logits, topkp, toktk);
    orch_init<<<1, 64, 0, stream>>>(topkp, toktk, scores, sflat, tflat, pflat, cur, outid);
    build_x<<<80, 256, 0, stream>>>(X, Wemb, cur, lastH, nullptr, 10);

    // ---- Tree expansion loop ----
    for (int i = 0; i < 5; i++) {
        init3<<<(40960 + 40960 + 320000 + 255) / 256, 256, 0, stream>>>(H1, bfc, 40960, H2, bm, 40960, logits, 320000);
        gemm_xwT<10><<<dim3(64, 8), 256, 10 * 1024 * 4, stream>>>(X, Wfc, H1, 4096, 8192, 1024);
        gemm_xwT<10><<<dim3(64, 4), 256, 10 * 1024 * 4, stream>>>(H1, Wm, H2, 4096, 4096, 1024);
        tanh_k<<<160, 256, 0, stream>>>(H2, 40960);
        gemm_xwT<10><<<dim3(500, 4), 256, 10 * 1024 * 4, stream>>>(H2, Whead, logits, 32000, 4096, 1024);
        topk_rows<<<10, 256, 0, stream>>>(logits, topkp, toktk);
        orch_iter<<<1, 128, 0, stream>>>(topkp, toktk, scores, sflat, tflat, pflat, cur, outid, i);
        if (i < 4) build_x<<<80, 256, 0, stream>>>(X, Wemb, cur, H2, outid, 10);
    }
    finalize<<<1, 64, 0, stream>>>(sflat, tflat, pflat, input_ids, out);
}